// Round 1
// 287.909 us; speedup vs baseline: 1.1073x; 1.1073x over previous
//
#include <hip/hip_runtime.h>
#include <hip/hip_bf16.h>

// Problem constants
#define B_ 16
#define T_ 1024
#define D_ 1024

using frag8  = __attribute__((ext_vector_type(8))) short;   // 8 bf16 (4 VGPRs)
using f32x4  = __attribute__((ext_vector_type(4))) float;   // 4 fp32 acc
using u16x8  = __attribute__((ext_vector_type(8))) unsigned short; // 16B chunk

__device__ inline unsigned short f2bf(float f) {
    union { float f; unsigned u; } v; v.f = f;
    unsigned r = v.u + 0x7FFF + ((v.u >> 16) & 1);   // round-nearest-even
    return (unsigned short)(r >> 16);
}
__device__ inline float bf2f(unsigned short u) {
    union { unsigned u; float f; } v; v.u = ((unsigned)u) << 16;
    return v.f;
}

// ---------------------------------------------------------------------------
// K0a: plain-cast Wq/Wk/Wv/Wfc fp32 -> bf16 (no transpose; all used k-major).
// grid 4096: w = bx>>10 selects the weight.
// ---------------------------------------------------------------------------
__global__ __launch_bounds__(256)
void cvt_w4(const float* __restrict__ Wq, const float* __restrict__ Wk,
            const float* __restrict__ Wv, const float* __restrict__ Wfc,
            unsigned short* __restrict__ wqb, unsigned short* __restrict__ wkb,
            unsigned short* __restrict__ wvb, unsigned short* __restrict__ wfcb) {
    const int w = blockIdx.x >> 10;
    const float* src = (w == 0) ? Wq : (w == 1) ? Wk : (w == 2) ? Wv : Wfc;
    unsigned short* dst = (w == 0) ? wqb : (w == 1) ? wkb : (w == 2) ? wvb : wfcb;
    int i = (blockIdx.x & 1023) * 256 + threadIdx.x;
    float4 v = ((const float4*)src)[i];
    ushort4 o;
    o.x = f2bf(v.x); o.y = f2bf(v.y); o.z = f2bf(v.z); o.w = f2bf(v.w);
    ((ushort4*)dst)[i] = o;
}

// ---------------------------------------------------------------------------
// K0b: weight-bias vectors (fp32, exact):
//  y=0: w1[e] = Wk[e]·bq     y=1: w2[e] = Wq[e]·bk
//  y=2: c[q]  = Wfc_row(q)·bv   y=3 (block 0 only): bkbq = bk·bq
// grid (256, 4), block 256 (4 waves, 1 row/wave).
// ---------------------------------------------------------------------------
__global__ __launch_bounds__(256)
void wvec(const float* __restrict__ Wq, const float* __restrict__ Wk,
          const float* __restrict__ Wfc,
          const float* __restrict__ bq, const float* __restrict__ bk,
          const float* __restrict__ bv,
          float* __restrict__ w1, float* __restrict__ w2,
          float* __restrict__ cvec, float* __restrict__ bkbq) {
    const int y = blockIdx.y;
    const int tid = threadIdx.x, lane = tid & 63, wave = tid >> 6;
    if (y == 3) {
        if (blockIdx.x != 0) return;
        float s = 0.f;
#pragma unroll
        for (int p = 0; p < 4; ++p) { int i = tid + p * 256; s += bk[i] * bq[i]; }
#pragma unroll
        for (int off = 32; off; off >>= 1) s += __shfl_down(s, off);
        __shared__ float sm[4];
        if (lane == 0) sm[wave] = s;
        __syncthreads();
        if (tid == 0) bkbq[0] = sm[0] + sm[1] + sm[2] + sm[3];
        return;
    }
    const float* Wsrc; const float* bvv; float* outp;
    if (y == 0)      { Wsrc = Wk;  bvv = bq; outp = w1; }
    else if (y == 1) { Wsrc = Wq;  bvv = bk; outp = w2; }
    else             { Wsrc = Wfc; bvv = bv; outp = cvec; }
    const int row = blockIdx.x * 4 + wave;
    const float* r = Wsrc + (size_t)row * D_;
    float s = 0.f;
#pragma unroll
    for (int it = 0; it < 4; ++it) {
        float4 a = *(const float4*)&r[it * 256 + lane * 4];
        float4 b = *(const float4*)&bvv[it * 256 + lane * 4];
        s += a.x * b.x + a.y * b.y + a.z * b.z + a.w * b.w;
    }
#pragma unroll
    for (int off = 32; off; off >>= 1) s += __shfl_down(s, off);
    if (lane == 0) outp[row] = s;
}

// ---------------------------------------------------------------------------
// K0c: FUSED x fp32 -> bf16 cast + u/v row dots (single pass over x).
//  xb[row] = bf16(x[row]);  u[row] = x[row]·w1;  v[row] = x[row]·w2 + bkbq.
// grid 4096, block 256 (4 waves, 1 row/wave); coalesced float4/ushort4.
// ---------------------------------------------------------------------------
__global__ __launch_bounds__(256)
void cvt_x_uv(const float* __restrict__ x, unsigned short* __restrict__ xb,
              const float* __restrict__ w1, const float* __restrict__ w2,
              const float* __restrict__ bkbq,
              float* __restrict__ u, float* __restrict__ v) {
    __shared__ float s1[1024], s2[1024];
    const int tid = threadIdx.x, lane = tid & 63, wave = tid >> 6;
#pragma unroll
    for (int p = 0; p < 4; ++p) {
        int i = tid + p * 256;
        s1[i] = w1[i]; s2[i] = w2[i];
    }
    __syncthreads();
    const int row = blockIdx.x * 4 + wave;
    const float* xr = x + (size_t)row * D_;
    unsigned short* xo = xb + (size_t)row * D_;
    float du = 0.f, dv = 0.f;
#pragma unroll
    for (int k = 0; k < 4; ++k) {
        const int e0 = k * 256 + lane * 4;
        float4 a = *(const float4*)&xr[e0];
        ushort4 o;
        o.x = f2bf(a.x); o.y = f2bf(a.y); o.z = f2bf(a.z); o.w = f2bf(a.w);
        *(ushort4*)&xo[e0] = o;
        du += a.x * s1[e0] + a.y * s1[e0 + 1] + a.z * s1[e0 + 2] + a.w * s1[e0 + 3];
        dv += a.x * s2[e0] + a.y * s2[e0 + 1] + a.z * s2[e0 + 2] + a.w * s2[e0 + 3];
    }
#pragma unroll
    for (int off = 32; off; off >>= 1) {
        du += __shfl_down(du, off);
        dv += __shfl_down(dv, off);
    }
    if (lane == 0) { u[row] = du; v[row] = dv + bkbq[0]; }
}

// ---------------------------------------------------------------------------
// K1: small weight-product GEMMs (m97-style), 1024x1024x1024 each:
//  z=0: NT[f][e] = sum_d Wq[f][d]·Wk[e][d]   -> ntb
//  z=1: M [q][e] = sum_d Wfc[q][d]·Wv[e][d]  -> mb
// grid (8, 8, 2) block 256.
// ---------------------------------------------------------------------------
__global__ __launch_bounds__(256)
void small_gemm(const unsigned short* __restrict__ wqb,
                const unsigned short* __restrict__ wkb,
                const unsigned short* __restrict__ wfcb,
                const unsigned short* __restrict__ wvb,
                unsigned short* __restrict__ ntb,
                unsigned short* __restrict__ mb) {
    __shared__ __align__(16) unsigned short As[128 * 32];
    __shared__ __align__(16) unsigned short Bs[128 * 32];

    const int z  = blockIdx.z;
    const int n0 = blockIdx.x * 128;
    const int m0 = blockIdx.y * 128;
    const unsigned short* A  = z ? wfcb : wqb;
    const unsigned short* Bm = z ? wvb  : wkb;
    unsigned short* out = z ? mb : ntb;

    const int tid = threadIdx.x, lane = tid & 63, wave = tid >> 6;
    const int wm = (wave >> 1) * 64, wn = (wave & 1) * 64;

    f32x4 acc[4][4];
#pragma unroll
    for (int i = 0; i < 4; i++)
#pragma unroll
        for (int j = 0; j < 4; j++) acc[i][j] = (f32x4){0.f, 0.f, 0.f, 0.f};

    const int srow = lane >> 2;
    const int sk   = (lane & 3) * 8;
    const int fr = lane & 15, fk = (lane >> 4) * 8;

    for (int k0 = 0; k0 < D_; k0 += 32) {
#pragma unroll
        for (int it = 0; it < 2; ++it) {
            const int rb = wave * 2 + it;
            const int r  = rb * 16 + srow;
            __builtin_amdgcn_global_load_lds(
                (const __attribute__((address_space(1))) unsigned int*)
                    (A + (size_t)(m0 + r) * D_ + k0 + sk),
                (__attribute__((address_space(3))) unsigned int*)(As + rb * 512),
                16, 0, 0);
            __builtin_amdgcn_global_load_lds(
                (const __attribute__((address_space(1))) unsigned int*)
                    (Bm + (size_t)(n0 + r) * D_ + k0 + sk),
                (__attribute__((address_space(3))) unsigned int*)(Bs + rb * 512),
                16, 0, 0);
        }
        __syncthreads();

        frag8 af[4], bff[4];
#pragma unroll
        for (int t = 0; t < 4; ++t)
            af[t] = *(const frag8*)&As[(wm + t * 16 + fr) * 32 + fk];
#pragma unroll
        for (int t = 0; t < 4; ++t)
            bff[t] = *(const frag8*)&Bs[(wn + t * 16 + fr) * 32 + fk];
#pragma unroll
        for (int i = 0; i < 4; i++)
#pragma unroll
            for (int j = 0; j < 4; j++)
                acc[i][j] = __builtin_amdgcn_mfma_f32_16x16x32_bf16(
                    af[i], bff[j], acc[i][j], 0, 0, 0);
        __syncthreads();
    }

    const int col   = lane & 15;
    const int rbase = (lane >> 4) * 4;
#pragma unroll
    for (int i = 0; i < 4; i++) {
#pragma unroll
        for (int j = 0; j < 4; j++) {
            int gn = n0 + wn + j * 16 + col;
#pragma unroll
            for (int r = 0; r < 4; r++) {
                int gm = m0 + wm + i * 16 + rbase + r;
                out[(size_t)gm * D_ + gn] = f2bf(acc[i][j][r]);
            }
        }
    }
}

// ---------------------------------------------------------------------------
// K2 (NEW): fused P/G GEMM, 256x256-tile 8-phase schedule (m201 template).
// Both GEMMs share A = xb (M=16384, K=1024, N=1024):
//  z=0: P[i][f] = sum_e x[i][e]·NT[f][e]           -> pb (row-major bf16)
//  z=1: G[i][q] = sum_e x[i][e]·M[q][e] + c[q]     -> gbuf (OLD fragment
//       swizzle, bit-compatible with score_attn's consumption).
//
// Structure per guide §5 (T2+T3+T4+T5):
//  - 512 thr = 8 waves (2M x 4N); per-wave output 128x64 (acc[8][4]).
//  - BK=64; LDS = 2 dbuf x {A-h0,A-h1,B-h0,B-h1} x 16KB = 128 KiB (dynamic).
//  - LDS XOR swizzle byte^=((row&7)<<4): global source pre-swizzled (DMA
//    writes linearly), ds_read applies same XOR -> conflict-free b128 reads.
//  - 4 phases/K-tile: P0 {read A(i0)+all B; stage (T+1).Ah1}, P1 {stage
//    (T+2).Bh0}, P2 {read A(i1); stage (T+2).Bh1}, P3 {stage (T+2).Ah0;
//    vmcnt(6)}.  Region-safety: B halves of tile T are fully read in T.P0,
//    A halves in T.P2; every stage lands >=1 end-barrier after the last
//    read of its region.  vmcnt(6) at P3 leaves exactly 3 half-tiles in
//    flight and guarantees tile T+1 fully resident (induction from the
//    7-half prologue).  Raw s_barrier (no vmcnt drain) + sched_barrier(0)
//    pins phase boundaries; tail stages clamp k to the last tile (never
//    read; regions free by the same map).
// grid 512 blocks; XCD swizzle: logical = mt*8 + z*4 + nt so each XCD
// keeps an A-panel L2-resident across both z and all nt.
// ---------------------------------------------------------------------------
#define BARRIER() do { __builtin_amdgcn_s_barrier(); \
                       __builtin_amdgcn_sched_barrier(0); } while (0)

__global__ __launch_bounds__(512, 2)
void pg_gemm8(const unsigned short* __restrict__ xb,
              const unsigned short* __restrict__ ntb,
              const unsigned short* __restrict__ mb,
              const float* __restrict__ cvec,
              unsigned short* __restrict__ pb,
              unsigned short* __restrict__ gbuf) {
    extern __shared__ __align__(16) unsigned short lds_pg[];

    const int bid = blockIdx.x;
    const int logical = (bid & 7) * 64 + (bid >> 3);
    const int mt = logical >> 3;          // 0..63
    const int z  = (logical >> 2) & 1;
    const int nt = logical & 3;           // 0..3
    const int m0 = mt * 256, n0 = nt * 256;

    const unsigned short* A  = xb;
    const unsigned short* Bm = z ? mb : ntb;

    const int tid = threadIdx.x, lane = tid & 63, w = tid >> 6;
    const int fr = lane & 15, ls = lane >> 4, f7 = fr & 7;

    // staging: LDS linear slot L = it*8192B + tid*16B -> row R=L>>7,
    // lds-slot (L>>4)&7; source slot s = ldsslot ^ (R&7)  (inverse swizzle)
    const int ssl   = ((tid & 7) ^ ((tid >> 3) & 7)) * 8;      // elements
    const int soff0 = (tid >> 3) * 1024 + ssl;
    const int soff1 = soff0 + 64 * 1024;
    const int dstw  = w * 512;                                 // u16

    const unsigned short* pA0 = A   + (size_t)m0 * 1024;
    const unsigned short* pA1 = pA0 + (size_t)128 * 1024;
    const unsigned short* pB0 = Bm  + (size_t)n0 * 1024;
    const unsigned short* pB1 = pB0 + (size_t)128 * 1024;

#define STG(ldsoff, panel, kcol)                                               \
    do {                                                                       \
        __builtin_amdgcn_global_load_lds(                                      \
            (const __attribute__((address_space(1))) unsigned int*)            \
                ((panel) + soff0 + (kcol)),                                    \
            (__attribute__((address_space(3))) unsigned int*)                  \
                (lds_pg + (ldsoff) + dstw), 16, 0, 0);                         \
        __builtin_amdgcn_global_load_lds(                                      \
            (const __attribute__((address_space(1))) unsigned int*)            \
                ((panel) + soff1 + (kcol)),                                    \
            (__attribute__((address_space(3))) unsigned int*)                  \
                (lds_pg + (ldsoff) + 4096 + dstw), 16, 0, 0);                  \
    } while (0)

    // prologue: tile0 fully into buf0; tile1 {Bh0,Bh1,Ah0} into buf1
    STG(0,             pA0, 0);
    STG(8192,          pA1, 0);
    STG(16384,         pB0, 0);
    STG(24576,         pB1, 0);
    STG(32768 + 16384, pB0, 64);
    STG(32768 + 24576, pB1, 64);
    STG(32768 + 0,     pA0, 64);
    asm volatile("s_waitcnt vmcnt(6)" ::: "memory");
    BARRIER();

    f32x4 acc[8][4];
#pragma unroll
    for (int i = 0; i < 8; i++)
#pragma unroll
        for (int j = 0; j < 4; j++) acc[i][j] = (f32x4){0.f, 0.f, 0.f, 0.f};

    const int aregw = (w >> 2) * 8192;                  // wave's A half
    const int bregw = 16384 + ((w & 3) >> 1) * 8192;    // wave's B half
    const int bro   = (w & 1) * 64;                     // n-offset in B half
    const int sl0   = (ls ^ f7) << 3;                   // kk=0 swz slot (elems)
    const int sl1   = ((4 + ls) ^ f7) << 3;             // kk=1

    frag8 af[4][2], bf[4][2];

#define LDA(IH)                                                                \
    _Pragma("unroll")                                                          \
    for (int t = 0; t < 4; ++t) {                                              \
        const int rbb = abase + ((IH) * 64 + t * 16 + fr) * 64;                \
        af[t][0] = *(const frag8*)&lds_pg[rbb + sl0];                          \
        af[t][1] = *(const frag8*)&lds_pg[rbb + sl1];                          \
    }
#define LDBALL()                                                               \
    _Pragma("unroll")                                                          \
    for (int j = 0; j < 4; ++j) {                                              \
        const int rbb = bbase + (bro + j * 16 + fr) * 64;                      \
        bf[j][0] = *(const frag8*)&lds_pg[rbb + sl0];                          \
        bf[j][1] = *(const frag8*)&lds_pg[rbb + sl1];                          \
    }
#define MFMA_Q(I0, J0)                                                         \
    __builtin_amdgcn_s_setprio(1);                                             \
    _Pragma("unroll")                                                          \
    for (int t = 0; t < 4; ++t) {                                              \
        _Pragma("unroll")                                                      \
        for (int jj = 0; jj < 2; ++jj) {                                       \
            acc[(I0)+t][(J0)+jj] = __builtin_amdgcn_mfma_f32_16x16x32_bf16(    \
                af[t][0], bf[(J0)+jj][0], acc[(I0)+t][(J0)+jj], 0, 0, 0);      \
            acc[(I0)+t][(J0)+jj] = __builtin_amdgcn_mfma_f32_16x16x32_bf16(    \
                af[t][1], bf[(J0)+jj][1], acc[(I0)+t][(J0)+jj], 0, 0, 0);      \
        }                                                                      \
    }                                                                          \
    __builtin_amdgcn_s_setprio(0);

    for (int T = 0; T < 16; ++T) {
        const int cbase = (T & 1) << 15;      // current buf (u16 offset)
        const int obase = cbase ^ 32768;      // other buf
        const int abase = cbase + aregw;
        const int bbase = cbase + bregw;
        const int kc1 = (T + 1 < 16 ? T + 1 : 15) * 64;
        const int kc2 = (T + 2 < 16 ? T + 2 : 15) * 64;

        // P0: read A(i-half0) + all B; stage (T+1).Ah1 (other buf)
        LDA(0)
        LDBALL()
        STG(obase + 8192, pA1, kc1);
        BARRIER();
        MFMA_Q(0, 0)
        BARRIER();

        // P1: stage (T+2).Bh0 (this buf; B fully read in P0)
        STG(cbase + 16384, pB0, kc2);
        BARRIER();
        MFMA_Q(0, 2)
        BARRIER();

        // P2: read A(i-half1); stage (T+2).Bh1
        LDA(1)
        STG(cbase + 24576, pB1, kc2);
        BARRIER();
        MFMA_Q(4, 2)
        BARRIER();

        // P3: stage (T+2).Ah0 (A fully read in P2); counted vmcnt
        STG(cbase + 0, pA0, kc2);
        asm volatile("s_waitcnt vmcnt(6)" ::: "memory");
        BARRIER();
        MFMA_Q(4, 0)
        BARRIER();
    }

    // drain outstanding (clamped tail) LDS-DMA before workgroup can exit
    asm volatile("s_waitcnt vmcnt(0)" ::: "memory");

    // epilogue
    const int wm = (w >> 2) * 128, wn = (w & 3) * 64;
    const int rb4 = ls * 4;
    if (z == 0) {
        // P: row-major store (consumed via global_load_lds row staging)
#pragma unroll
        for (int i = 0; i < 8; ++i)
#pragma unroll
            for (int j = 0; j < 4; ++j) {
                const int gm = m0 + wm + i * 16 + rb4;
                const int gn = n0 + wn + j * 16 + fr;
#pragma unroll
                for (int r = 0; r < 4; ++r)
                    pb[(size_t)(gm + r) * 1024 + gn] = f2bf(acc[i][j][r]);
            }
    } else {
        // G: write the OLD 128x128-tile fragment swizzle so score_attn's
        // consumption is bit-identical.  For element (row,col) in tile:
        //  wave_old = (row>>6)*2 | (col>>6); lane_old = lane (proof: low
        //  bits match); f = (row>>4&3)*16 + (col>>4&3)*4 + (row&3);
        //  addr = tile*16384 + (f>>3)*2048 + tid_old*8 + (f&7).
        float bb[4];
#pragma unroll
        for (int j = 0; j < 4; ++j) bb[j] = cvec[n0 + wn + j * 16 + fr];
        const int mblk = (m0 >> 7) + (w >> 2);
#pragma unroll
        for (int i = 0; i < 8; ++i) {
#pragma unroll
            for (int j = 0; j < 4; ++j) {
                const int colblk = wn + j * 16;
                const int nblk = (n0 >> 7) + (colblk >> 7);
                const size_t tile = ((size_t)(mblk * 8 + nblk)) << 14;
                const int wave_old = ((i >> 2) << 1) | ((colblk >> 6) & 1);
                const int c_old = ((i & 3) << 1) | (j >> 1);
                const size_t off = tile + (size_t)c_old * 2048
                                 + (size_t)(wave_old * 64 + lane) * 8
                                 + (j & 1) * 4;
                ushort4 o;
                o.x = f2bf(acc[i][j][0] + bb[j]);
                o.y = f2bf(acc[i][j][1] + bb[j]);
                o.z = f2bf(acc[i][j][2] + bb[j]);
                o.w = f2bf(acc[i][j][3] + bb[j]);
                *(ushort4*)(gbuf + off) = o;
            }
        }
    }
#undef STG
#undef LDA
#undef LDBALL
#undef MFMA_Q
}

// ---------------------------------------------------------------------------
// K3: score + exp + G-weighted row reduction — DETERMINISTIC (no atomics).
// S[i][j] = sum_f P[b·T+i][f]·x[b·T+j][f] + u[b·T+i] + v[b·T+j]
// p = exp(S*scale).  G read from the fragment-swizzled gbuf (8 coalesced
// b128 loads/lane).  Each block writes per-column-half row partials:
// lpart/Apart[(((b*8+i0b)*8+j0b)*2+half)*128 + row] — every slot written
// exactly once; finalize sums in fixed order.  grid (8,8,16) block 256.
// ---------------------------------------------------------------------------
__global__ __launch_bounds__(256)
void score_attn(const unsigned short* __restrict__ pbuf,
                const unsigned short* __restrict__ xb,
                const unsigned short* __restrict__ gb,
                const float* __restrict__ u, const float* __restrict__ v,
                float* __restrict__ lpart, float* __restrict__ Apart) {
    __shared__ __align__(16) unsigned short Ks[128 * 32];
    __shared__ __align__(16) unsigned short Qs[128 * 32];

    const int l   = blockIdx.x + 8 * blockIdx.y + 64 * blockIdx.z;
    const int xcd = l & 7;
    const int uix = l >> 3;            // 0..127
    const int i0b = uix >> 4;          // 0..7  (i0 outer)
    const int mid = uix & 15;
    const int b   = xcd * 2 + (mid >> 3);
    const int j0b = mid & 7;           // j0 inner
    const int i0 = i0b * 128, j0 = j0b * 128;

    const unsigned short* P = pbuf + ((size_t)b * T_ + i0) * D_;
    const unsigned short* X = xb   + ((size_t)b * T_ + j0) * D_;

    const int tid = threadIdx.x, lane = tid & 63, wave = tid >> 6;
    const int wm = (wave >> 1) * 64, wn = (wave & 1) * 64;

    f32x4 accS[4][4];
#pragma unroll
    for (int i = 0; i < 4; i++)
#pragma unroll
        for (int j = 0; j < 4; j++) accS[i][j] = (f32x4){0.f, 0.f, 0.f, 0.f};

    const int srow = lane >> 2;
    const int sk   = (lane & 3) * 8;
    const int fr = lane & 15, fk = (lane >> 4) * 8;

    for (int k0 = 0; k0 < D_; k0 += 32) {
#pragma unroll
        for (int it = 0; it < 2; ++it) {
            const int rb = wave * 2 + it;
            const int r  = rb * 16 + srow;
            __builtin_amdgcn_global_load_lds(
                (const __attribute__((address_space(1))) unsigned int*)
                    (P + (size_t)r * D_ + k0 + sk),
                (__attribute__((address_space(3))) unsigned int*)(Ks + rb * 512),
                16, 0, 0);
            __builtin_amdgcn_global_load_lds(
                (const __attribute__((address_space(1))) unsigned int*)
                    (X + (size_t)r * D_ + k0 + sk),
                (__attribute__((address_space(3))) unsigned int*)(Qs + rb * 512),
                16, 0, 0);
        }
        __syncthreads();

        frag8 af[4], bff[4];
#pragma unroll
        for (int t = 0; t < 4; ++t)
            af[t] = *(const frag8*)&Ks[(wm + t * 16 + fr) * 32 + fk];
#pragma unroll
        for (int t = 0; t < 4; ++t)
            bff[t] = *(const frag8*)&Qs[(wn + t * 16 + fr) * 32 + fk];
#pragma unroll
        for (int i = 0; i < 4; i++)
#pragma unroll
            for (int j = 0; j < 4; j++)
                accS[i][j] = __builtin_amdgcn_mfma_f32_16x16x32_bf16(
                    af[i], bff[j], accS[i][j], 0, 0, 0);
        __syncthreads();
    }

    // epilogue: S += u[i]+v[j]; p = exp(S*scale); pair with swizzled G
    const float scale = 0.03125f;   // 1/sqrt(1024)
    const int col   = lane & 15;
    const int rbase = (lane >> 4) * 4;
    const float* ub = u + (size_t)b * T_ + i0;
    const float* vb = v + (size_t)b * T_ + j0;

    float vval[4];
#pragma unroll
    for (int j = 0; j < 4; j++) vval[j] = vb[wn + j * 16 + col];
    float uval[4][4];
#pragma unroll
    for (int i = 0; i < 4; i++)
#pragma unroll
        for (int r = 0; r < 4; r++) uval[i][r] = ub[wm + i * 16 + rbase + r];

    float l_part[4][4], A_part[4][4];
#pragma unroll
    for (int i = 0; i < 4; i++)
#pragma unroll
        for (int r = 0; r < 4; r++) { l_part[i][r] = 0.f; A_part[i][r] = 0.f; }

    const unsigned short* Gt =
        gb + (((size_t)(b * 8 + i0b) * 8 + j0b) << 14) + tid * 8;
#pragma unroll
    for (int c = 0; c < 8; ++c) {
        u16x8 gv = *(const u16x8*)(Gt + (size_t)c * 2048);
        const int i = c >> 1;
#pragma unroll
        for (int e = 0; e < 8; ++e) {
            const int f  = c * 8 + e;
            const int jj = (f >> 2) & 3;
            const int r  = f & 3;
            float p = __expf((accS[i][jj][r] + uval[i][r] + vval[jj]) * scale);
            float g = bf2f(gv[e]);
            l_part[i][r] += p;
            A_part[i][r] += p * g;
        }
    }

#pragma unroll
    for (int m = 1; m < 16; m <<= 1) {
#pragma unroll
        for (int i = 0; i < 4; i++)
#pragma unroll
            for (int r = 0; r < 4; r++) {
                l_part[i][r] += __shfl_xor(l_part[i][r], m);
                A_part[i][r] += __shfl_xor(A_part[i][r], m);
            }
    }

    if ((lane & 15) == 0) {
        const int half = wave & 1;     // wn half: cols 0..63 vs 64..127
        const size_t base =
            ((((size_t)b * 8 + i0b) * 8 + j0b) * 2 + half) * 128;
        float* lrow = lpart + base;
        float* Arow = Apart + base;
#pragma unroll
        for (int i = 0; i < 4; i++)
#pragma unroll
            for (int r = 0; r < 4; r++) {
                int row = wm + i * 16 + rbase + r;
                lrow[row] = l_part[i][r];
                Arow[row] = A_part[i][r];
            }
    }
}

// ---------------------------------------------------------------------------
// K4: finalize — out[b] = bfc + sum_i (sum_t Apart)/(sum_t lpart).
// Fixed summation order -> bit-deterministic.  grid (16) block 256.
// ---------------------------------------------------------------------------
__global__ __launch_bounds__(256)
void finalize(const float* __restrict__ lpart, const float* __restrict__ Apart,
              const float* __restrict__ bfc, float* __restrict__ out) {
    const int b = blockIdx.x;
    const int tid = threadIdx.x, lane = tid & 63, wave = tid >> 6;
    float s = 0.f;
#pragma unroll
    for (int p = 0; p < 4; ++p) {
        const int rg = tid + p * 256;          // 0..1023 (row index within b)
        const int i0b = rg >> 7, row = rg & 127;
        const size_t base = ((size_t)b * 8 + i0b) * 2048 + row;
        float lsum = 0.f, Asum = 0.f;
#pragma unroll
        for (int t = 0; t < 16; ++t) {         // j0b*2 + half, fixed order
            lsum += lpart[base + (size_t)t * 128];
            Asum += Apart[base + (size_t)t * 128];
        }
        s += Asum / lsum;
    }
#pragma unroll
    for (int off = 32; off; off >>= 1) s += __shfl_down(s, off);
    __shared__ float ws_[4];
    if (lane == 0) ws_[wave] = s;
    __syncthreads();
    if (tid == 0) out[b] = ws_[0] + ws_[1] + ws_[2] + ws_[3] + bfc[0];
}

extern "C" void kernel_launch(void* const* d_in, const int* in_sizes, int n_in,
                              void* d_out, int out_size, void* d_ws, size_t ws_size,
                              hipStream_t stream) {
    const float* x   = (const float*)d_in[0];
    const float* Wq  = (const float*)d_in[1];
    const float* bq  = (const float*)d_in[2];
    const float* Wk  = (const float*)d_in[3];
    const float* bk  = (const float*)d_in[4];
    const float* Wv  = (const float*)d_in[5];
    const float* bv  = (const float*)d_in[6];
    const float* Wfc = (const float*)d_in[7];
    const float* bfc = (const float*)d_in[8];
    float* out = (float*)d_out;

    // one-time: allow 128 KiB dynamic LDS for pg_gemm8 (host-side, capture-safe)
    static bool attr_set = false;
    if (!attr_set) {
        hipFuncSetAttribute((const void*)pg_gemm8,
                            hipFuncAttributeMaxDynamicSharedMemorySize, 131072);
        attr_set = true;
    }

    // workspace layout (~110.4 MB), every byte written before read each call:
    char* ws = (char*)d_ws;
    unsigned short* xb    = (unsigned short*)ws;                   // 32 MB
    unsigned short* wqb   = xb   + (size_t)B_ * T_ * D_;           // 2 MB
    unsigned short* wkb   = wqb  + (size_t)D_ * D_;                // 2 MB
    unsigned short* wvb   = wkb  + (size_t)D_ * D_;                // 2 MB
    unsigned short* wfcb  = wvb  + (size_t)D_ * D_;                // 2 MB
    unsigned short* ntb   = wfcb + (size_t)D_ * D_;                // 2 MB
    unsigned short* mb    = ntb  + (size_t)D_ * D_;                // 2 MB
    unsigned short* pb    = mb   + (size_t)D_ * D_;                // 32 MB
    unsigned short* gbuf  = pb   + (size_t)B_ * T_ * D_;           // 32 MB
    float*          w1    = (float*)(gbuf + (size_t)B_ * T_ * T_); // 4 KB
    float*          w2    = w1 + D_;                               // 4 KB
    float*          cvec  = w2 + D_;                               // 4 KB
    float*          bkbq  = cvec + D_;                             // 16 B
    float*          u     = bkbq + 4;                              // 64 KB
    float*          v     = u + (size_t)B_ * T_;                   // 64 KB
    float*          lpart = v + (size_t)B_ * T_;                   // 1 MB
    float*          Apart = lpart + (size_t)B_ * 8 * 8 * 2 * 128;  // 1 MB

    cvt_w4    <<<dim3(4096),      256, 0,      stream>>>(Wq, Wk, Wv, Wfc, wqb, wkb, wvb, wfcb);
    wvec      <<<dim3(256, 4),    256, 0,      stream>>>(Wq, Wk, Wfc, bq, bk, bv, w1, w2, cvec, bkbq);
    cvt_x_uv  <<<dim3(4096),      256, 0,      stream>>>(x, xb, w1, w2, bkbq, u, v);
    small_gemm<<<dim3(8, 8, 2),   256, 0,      stream>>>(wqb, wkb, wfcb, wvb, ntb, mb);
    pg_gemm8  <<<dim3(512),       512, 131072, stream>>>(xb, ntb, mb, cvec, pb, gbuf);
    score_attn<<<dim3(8, 8, 16),  256, 0,      stream>>>(pb, xb, gbuf, u, v, lpart, Apart);
    finalize  <<<dim3(B_),        256, 0,      stream>>>(lpart, Apart, bfc, out);
}

// Round 2
// 273.511 us; speedup vs baseline: 1.1656x; 1.0526x over previous
//
#include <hip/hip_runtime.h>
#include <hip/hip_bf16.h>

// Problem constants
#define B_ 16
#define T_ 1024
#define D_ 1024

using frag8  = __attribute__((ext_vector_type(8))) short;   // 8 bf16 (4 VGPRs)
using f32x4  = __attribute__((ext_vector_type(4))) float;   // 4 fp32 acc
using u16x8  = __attribute__((ext_vector_type(8))) unsigned short; // 16B chunk

__device__ inline unsigned short f2bf(float f) {
    union { float f; unsigned u; } v; v.f = f;
    unsigned r = v.u + 0x7FFF + ((v.u >> 16) & 1);   // round-nearest-even
    return (unsigned short)(r >> 16);
}
__device__ inline float bf2f(unsigned short u) {
    union { unsigned u; float f; } v; v.u = ((unsigned)u) << 16;
    return v.f;
}

// ---------------------------------------------------------------------------
// K0a: plain-cast Wq/Wk/Wv/Wfc fp32 -> bf16 (no transpose; all used k-major).
// grid 4096: w = bx>>10 selects the weight.
// ---------------------------------------------------------------------------
__global__ __launch_bounds__(256)
void cvt_w4(const float* __restrict__ Wq, const float* __restrict__ Wk,
            const float* __restrict__ Wv, const float* __restrict__ Wfc,
            unsigned short* __restrict__ wqb, unsigned short* __restrict__ wkb,
            unsigned short* __restrict__ wvb, unsigned short* __restrict__ wfcb) {
    const int w = blockIdx.x >> 10;
    const float* src = (w == 0) ? Wq : (w == 1) ? Wk : (w == 2) ? Wv : Wfc;
    unsigned short* dst = (w == 0) ? wqb : (w == 1) ? wkb : (w == 2) ? wvb : wfcb;
    int i = (blockIdx.x & 1023) * 256 + threadIdx.x;
    float4 v = ((const float4*)src)[i];
    ushort4 o;
    o.x = f2bf(v.x); o.y = f2bf(v.y); o.z = f2bf(v.z); o.w = f2bf(v.w);
    ((ushort4*)dst)[i] = o;
}

// ---------------------------------------------------------------------------
// K0b: weight-bias vectors (fp32, exact):
//  y=0: w1[e] = Wk[e]·bq     y=1: w2[e] = Wq[e]·bk
//  y=2: c[q]  = Wfc_row(q)·bv   y=3 (block 0 only): bkbq = bk·bq
// grid (256, 4), block 256 (4 waves, 1 row/wave).
// ---------------------------------------------------------------------------
__global__ __launch_bounds__(256)
void wvec(const float* __restrict__ Wq, const float* __restrict__ Wk,
          const float* __restrict__ Wfc,
          const float* __restrict__ bq, const float* __restrict__ bk,
          const float* __restrict__ bv,
          float* __restrict__ w1, float* __restrict__ w2,
          float* __restrict__ cvec, float* __restrict__ bkbq) {
    const int y = blockIdx.y;
    const int tid = threadIdx.x, lane = tid & 63, wave = tid >> 6;
    if (y == 3) {
        if (blockIdx.x != 0) return;
        float s = 0.f;
#pragma unroll
        for (int p = 0; p < 4; ++p) { int i = tid + p * 256; s += bk[i] * bq[i]; }
#pragma unroll
        for (int off = 32; off; off >>= 1) s += __shfl_down(s, off);
        __shared__ float sm[4];
        if (lane == 0) sm[wave] = s;
        __syncthreads();
        if (tid == 0) bkbq[0] = sm[0] + sm[1] + sm[2] + sm[3];
        return;
    }
    const float* Wsrc; const float* bvv; float* outp;
    if (y == 0)      { Wsrc = Wk;  bvv = bq; outp = w1; }
    else if (y == 1) { Wsrc = Wq;  bvv = bk; outp = w2; }
    else             { Wsrc = Wfc; bvv = bv; outp = cvec; }
    const int row = blockIdx.x * 4 + wave;
    const float* r = Wsrc + (size_t)row * D_;
    float s = 0.f;
#pragma unroll
    for (int it = 0; it < 4; ++it) {
        float4 a = *(const float4*)&r[it * 256 + lane * 4];
        float4 b = *(const float4*)&bvv[it * 256 + lane * 4];
        s += a.x * b.x + a.y * b.y + a.z * b.z + a.w * b.w;
    }
#pragma unroll
    for (int off = 32; off; off >>= 1) s += __shfl_down(s, off);
    if (lane == 0) outp[row] = s;
}

// ---------------------------------------------------------------------------
// K0c: FUSED x fp32 -> bf16 cast + u/v row dots (single pass over x).
//  xb[row] = bf16(x[row]);  u[row] = x[row]·w1;  v[row] = x[row]·w2 + bkbq.
// grid 4096, block 256 (4 waves, 1 row/wave); coalesced float4/ushort4.
// ---------------------------------------------------------------------------
__global__ __launch_bounds__(256)
void cvt_x_uv(const float* __restrict__ x, unsigned short* __restrict__ xb,
              const float* __restrict__ w1, const float* __restrict__ w2,
              const float* __restrict__ bkbq,
              float* __restrict__ u, float* __restrict__ v) {
    __shared__ float s1[1024], s2[1024];
    const int tid = threadIdx.x, lane = tid & 63, wave = tid >> 6;
#pragma unroll
    for (int p = 0; p < 4; ++p) {
        int i = tid + p * 256;
        s1[i] = w1[i]; s2[i] = w2[i];
    }
    __syncthreads();
    const int row = blockIdx.x * 4 + wave;
    const float* xr = x + (size_t)row * D_;
    unsigned short* xo = xb + (size_t)row * D_;
    float du = 0.f, dv = 0.f;
#pragma unroll
    for (int k = 0; k < 4; ++k) {
        const int e0 = k * 256 + lane * 4;
        float4 a = *(const float4*)&xr[e0];
        ushort4 o;
        o.x = f2bf(a.x); o.y = f2bf(a.y); o.z = f2bf(a.z); o.w = f2bf(a.w);
        *(ushort4*)&xo[e0] = o;
        du += a.x * s1[e0] + a.y * s1[e0 + 1] + a.z * s1[e0 + 2] + a.w * s1[e0 + 3];
        dv += a.x * s2[e0] + a.y * s2[e0 + 1] + a.z * s2[e0 + 2] + a.w * s2[e0 + 3];
    }
#pragma unroll
    for (int off = 32; off; off >>= 1) {
        du += __shfl_down(du, off);
        dv += __shfl_down(dv, off);
    }
    if (lane == 0) { u[row] = du; v[row] = dv + bkbq[0]; }
}

// ---------------------------------------------------------------------------
// K1: small weight-product GEMMs (m97-style), 1024x1024x1024 each:
//  z=0: NT[f][e] = sum_d Wq[f][d]·Wk[e][d]   -> ntb
//  z=1: M [q][e] = sum_d Wfc[q][d]·Wv[e][d]  -> mb
// grid (8, 8, 2) block 256.
// ---------------------------------------------------------------------------
__global__ __launch_bounds__(256)
void small_gemm(const unsigned short* __restrict__ wqb,
                const unsigned short* __restrict__ wkb,
                const unsigned short* __restrict__ wfcb,
                const unsigned short* __restrict__ wvb,
                unsigned short* __restrict__ ntb,
                unsigned short* __restrict__ mb) {
    __shared__ __align__(16) unsigned short As[128 * 32];
    __shared__ __align__(16) unsigned short Bs[128 * 32];

    const int z  = blockIdx.z;
    const int n0 = blockIdx.x * 128;
    const int m0 = blockIdx.y * 128;
    const unsigned short* A  = z ? wfcb : wqb;
    const unsigned short* Bm = z ? wvb  : wkb;
    unsigned short* out = z ? mb : ntb;

    const int tid = threadIdx.x, lane = tid & 63, wave = tid >> 6;
    const int wm = (wave >> 1) * 64, wn = (wave & 1) * 64;

    f32x4 acc[4][4];
#pragma unroll
    for (int i = 0; i < 4; i++)
#pragma unroll
        for (int j = 0; j < 4; j++) acc[i][j] = (f32x4){0.f, 0.f, 0.f, 0.f};

    const int srow = lane >> 2;
    const int sk   = (lane & 3) * 8;
    const int fr = lane & 15, fk = (lane >> 4) * 8;

    for (int k0 = 0; k0 < D_; k0 += 32) {
#pragma unroll
        for (int it = 0; it < 2; ++it) {
            const int rb = wave * 2 + it;
            const int r  = rb * 16 + srow;
            __builtin_amdgcn_global_load_lds(
                (const __attribute__((address_space(1))) unsigned int*)
                    (A + (size_t)(m0 + r) * D_ + k0 + sk),
                (__attribute__((address_space(3))) unsigned int*)(As + rb * 512),
                16, 0, 0);
            __builtin_amdgcn_global_load_lds(
                (const __attribute__((address_space(1))) unsigned int*)
                    (Bm + (size_t)(n0 + r) * D_ + k0 + sk),
                (__attribute__((address_space(3))) unsigned int*)(Bs + rb * 512),
                16, 0, 0);
        }
        __syncthreads();

        frag8 af[4], bff[4];
#pragma unroll
        for (int t = 0; t < 4; ++t)
            af[t] = *(const frag8*)&As[(wm + t * 16 + fr) * 32 + fk];
#pragma unroll
        for (int t = 0; t < 4; ++t)
            bff[t] = *(const frag8*)&Bs[(wn + t * 16 + fr) * 32 + fk];
#pragma unroll
        for (int i = 0; i < 4; i++)
#pragma unroll
            for (int j = 0; j < 4; j++)
                acc[i][j] = __builtin_amdgcn_mfma_f32_16x16x32_bf16(
                    af[i], bff[j], acc[i][j], 0, 0, 0);
        __syncthreads();
    }

    const int col   = lane & 15;
    const int rbase = (lane >> 4) * 4;
#pragma unroll
    for (int i = 0; i < 4; i++) {
#pragma unroll
        for (int j = 0; j < 4; j++) {
            int gn = n0 + wn + j * 16 + col;
#pragma unroll
            for (int r = 0; r < 4; r++) {
                int gm = m0 + wm + i * 16 + rbase + r;
                out[(size_t)gm * D_ + gn] = f2bf(acc[i][j][r]);
            }
        }
    }
}

// ---------------------------------------------------------------------------
// Shared 256x256 8-phase main-loop machinery (verified in round 1):
//  - 512 thr = 8 waves (2M x 4N); per-wave output 128x64 (acc[8][4]).
//  - BK=64; LDS = 2 dbuf x {A-h0,A-h1,B-h0,B-h1} x 16KB = 128 KiB (dynamic).
//  - LDS XOR swizzle byte^=((row&7)<<4): source pre-swizzled, reads XOR'd.
//  - Phases: P0 {read A(i0)+all B; stage (T+1).Ah1}, P1 {stage (T+2).Bh0},
//    P2 {read A(i1); stage (T+2).Bh1}, P3 {stage (T+2).Ah0; vmcnt(6)}.
//    Region-safety: B fully read in P0, A fully read by P2; every stage
//    lands >=1 end-barrier after the last read of its region; vmcnt(6) at
//    P3 drains the (T+1).Ah1 pair (needed at T+1.P0).  Tail stages clamp
//    kcol to the last tile (never read).
// ---------------------------------------------------------------------------
#define BARRIER() do { __builtin_amdgcn_s_barrier(); \
                       __builtin_amdgcn_sched_barrier(0); } while (0)

#define STG(ldsoff, panel, kcol)                                               \
    do {                                                                       \
        __builtin_amdgcn_global_load_lds(                                      \
            (const __attribute__((address_space(1))) unsigned int*)            \
                ((panel) + soff0 + (kcol)),                                    \
            (__attribute__((address_space(3))) unsigned int*)                  \
                (lds_pg + (ldsoff) + dstw), 16, 0, 0);                         \
        __builtin_amdgcn_global_load_lds(                                      \
            (const __attribute__((address_space(1))) unsigned int*)            \
                ((panel) + soff1 + (kcol)),                                    \
            (__attribute__((address_space(3))) unsigned int*)                  \
                (lds_pg + (ldsoff) + 4096 + dstw), 16, 0, 0);                  \
    } while (0)

#define LDA(IH)                                                                \
    _Pragma("unroll")                                                          \
    for (int t = 0; t < 4; ++t) {                                              \
        const int rbb = abase + ((IH) * 64 + t * 16 + fr) * 64;                \
        af[t][0] = *(const frag8*)&lds_pg[rbb + sl0];                          \
        af[t][1] = *(const frag8*)&lds_pg[rbb + sl1];                          \
    }
#define LDBALL()                                                               \
    _Pragma("unroll")                                                          \
    for (int j = 0; j < 4; ++j) {                                              \
        const int rbb = bbase + (bro + j * 16 + fr) * 64;                      \
        bf[j][0] = *(const frag8*)&lds_pg[rbb + sl0];                          \
        bf[j][1] = *(const frag8*)&lds_pg[rbb + sl1];                          \
    }
#define MFMA_Q(I0, J0)                                                         \
    __builtin_amdgcn_s_setprio(1);                                             \
    _Pragma("unroll")                                                          \
    for (int t = 0; t < 4; ++t) {                                              \
        _Pragma("unroll")                                                      \
        for (int jj = 0; jj < 2; ++jj) {                                       \
            acc[(I0)+t][(J0)+jj] = __builtin_amdgcn_mfma_f32_16x16x32_bf16(    \
                af[t][0], bf[(J0)+jj][0], acc[(I0)+t][(J0)+jj], 0, 0, 0);      \
            acc[(I0)+t][(J0)+jj] = __builtin_amdgcn_mfma_f32_16x16x32_bf16(    \
                af[t][1], bf[(J0)+jj][1], acc[(I0)+t][(J0)+jj], 0, 0, 0);      \
        }                                                                      \
    }                                                                          \
    __builtin_amdgcn_s_setprio(0);

#define MAIN_LOOP_8PHASE(PA0, PA1, PB0, PB1)                                   \
    STG(0,             PA0, 0);                                                \
    STG(8192,          PA1, 0);                                                \
    STG(16384,         PB0, 0);                                                \
    STG(24576,         PB1, 0);                                                \
    STG(32768 + 16384, PB0, 64);                                               \
    STG(32768 + 24576, PB1, 64);                                               \
    STG(32768 + 0,     PA0, 64);                                               \
    asm volatile("s_waitcnt vmcnt(6)" ::: "memory");                           \
    BARRIER();                                                                 \
    _Pragma("unroll")                                                          \
    for (int i = 0; i < 8; i++)                                                \
        _Pragma("unroll")                                                      \
        for (int j = 0; j < 4; j++) acc[i][j] = (f32x4){0.f, 0.f, 0.f, 0.f};   \
    for (int T = 0; T < 16; ++T) {                                             \
        const int cbase = (T & 1) << 15;                                       \
        const int obase = cbase ^ 32768;                                       \
        const int abase = cbase + aregw;                                       \
        const int bbase = cbase + bregw;                                       \
        const int kc1 = (T + 1 < 16 ? T + 1 : 15) * 64;                        \
        const int kc2 = (T + 2 < 16 ? T + 2 : 15) * 64;                        \
        LDA(0)                                                                 \
        LDBALL()                                                               \
        STG(obase + 8192, PA1, kc1);                                           \
        BARRIER();                                                             \
        MFMA_Q(0, 0)                                                           \
        BARRIER();                                                             \
        STG(cbase + 16384, PB0, kc2);                                          \
        BARRIER();                                                             \
        MFMA_Q(0, 2)                                                           \
        BARRIER();                                                             \
        LDA(1)                                                                 \
        STG(cbase + 24576, PB1, kc2);                                          \
        BARRIER();                                                             \
        MFMA_Q(4, 2)                                                           \
        BARRIER();                                                             \
        STG(cbase + 0, PA0, kc2);                                              \
        asm volatile("s_waitcnt vmcnt(6)" ::: "memory");                       \
        BARRIER();                                                             \
        MFMA_Q(4, 0)                                                           \
        BARRIER();                                                             \
    }                                                                          \
    asm volatile("s_waitcnt vmcnt(0)" ::: "memory");

// ---------------------------------------------------------------------------
// K2: fused P/G GEMM, 256x256-tile 8-phase.  A = xb (M=16384, K=1024):
//  z=0: P[i][f] = sum_e x[i][e]·NT[f][e]           -> pb (row-major bf16)
//  z=1: G[i][q] = sum_e x[i][e]·M[q][e] + c[q]     -> gbuf per-thread-slot
//       layout: tile(mt*4+nt)*65536 + (i*2+jp)*4096 + tid*8 + (j&1)*4 + r
//       (score_attn8 has identical block/wave/lane geometry -> reads the
//        exact slots back; 16B coalesced on both sides).
// grid 512; XCD swizzle keeps 8 consecutive A-panels per XCD.
// ---------------------------------------------------------------------------
__global__ __launch_bounds__(512, 2)
void pg_gemm8(const unsigned short* __restrict__ xb,
              const unsigned short* __restrict__ ntb,
              const unsigned short* __restrict__ mb,
              const float* __restrict__ cvec,
              unsigned short* __restrict__ pb,
              unsigned short* __restrict__ gbuf) {
    extern __shared__ __align__(16) unsigned short lds_pg[];

    const int bid = blockIdx.x;
    const int logical = (bid & 7) * 64 + (bid >> 3);
    const int mt = logical >> 3;          // 0..63
    const int z  = (logical >> 2) & 1;
    const int nt = logical & 3;           // 0..3
    const int m0 = mt * 256, n0 = nt * 256;

    const unsigned short* Bm = z ? mb : ntb;

    const int tid = threadIdx.x, lane = tid & 63, w = tid >> 6;
    const int fr = lane & 15, ls = lane >> 4, f7 = fr & 7;

    const int ssl   = ((tid & 7) ^ ((tid >> 3) & 7)) * 8;      // elements
    const int soff0 = (tid >> 3) * 1024 + ssl;
    const int soff1 = soff0 + 64 * 1024;
    const int dstw  = w * 512;                                 // u16

    const unsigned short* pA0 = xb  + (size_t)m0 * 1024;
    const unsigned short* pA1 = pA0 + (size_t)128 * 1024;
    const unsigned short* pB0 = Bm  + (size_t)n0 * 1024;
    const unsigned short* pB1 = pB0 + (size_t)128 * 1024;

    const int aregw = (w >> 2) * 8192;                  // wave's A half
    const int bregw = 16384 + ((w & 3) >> 1) * 8192;    // wave's B half
    const int bro   = (w & 1) * 64;                     // n-offset in B half
    const int sl0   = (ls ^ f7) << 3;                   // kk=0 swz slot (elems)
    const int sl1   = ((4 + ls) ^ f7) << 3;             // kk=1

    f32x4 acc[8][4];
    frag8 af[4][2], bf[4][2];

    MAIN_LOOP_8PHASE(pA0, pA1, pB0, pB1)

    // epilogue
    const int wm = (w >> 2) * 128, wn = (w & 3) * 64;
    const int rb4 = ls * 4;
    if (z == 0) {
        // P: row-major store (consumed via global_load_lds row staging)
#pragma unroll
        for (int i = 0; i < 8; ++i)
#pragma unroll
            for (int j = 0; j < 4; ++j) {
                const int gm = m0 + wm + i * 16 + rb4;
                const int gn = n0 + wn + j * 16 + fr;
#pragma unroll
                for (int r = 0; r < 4; ++r)
                    pb[(size_t)(gm + r) * 1024 + gn] = f2bf(acc[i][j][r]);
            }
    } else {
        // G: per-thread-slot layout, 16 coalesced 16B stores
        float bb[4];
#pragma unroll
        for (int j = 0; j < 4; ++j) bb[j] = cvec[n0 + wn + j * 16 + fr];
        unsigned short* Gt = gbuf + ((size_t)(mt * 4 + nt) << 16) + tid * 8;
#pragma unroll
        for (int i = 0; i < 8; ++i) {
#pragma unroll
            for (int jp = 0; jp < 2; ++jp) {
                u16x8 o;
#pragma unroll
                for (int e = 0; e < 8; ++e) {
                    const int j = jp * 2 + (e >> 2), r = e & 3;
                    o[e] = f2bf(acc[i][j][r] + bb[j]);
                }
                *(u16x8*)(Gt + (size_t)(i * 2 + jp) * 4096) = o;
            }
        }
    }
}

// ---------------------------------------------------------------------------
// K3 (NEW): score + exp + G-weighted row reduction, 256x256 8-phase.
// S[i][j] = sum_f P[b·T+i][f]·x[b·T+j][f] + u[i] + v[j]; p = exp(S*scale).
// A-panel = P rows (b*1024+it*256..+256), B-panel = X rows (b*1024+jt*256).
// G read back from per-thread-slot gbuf (identical geometry as producer).
// Partials: chunk t = jt*4+(w&3) covers cols [t*64,(t+1)*64) — same 64-col
// groups as before; lpart/Apart[((b*8+i0b)*16+t)*128+row], i0b=it*2+(w>>2),
// every slot written exactly once; finalize unchanged.  grid 256.
// ---------------------------------------------------------------------------
__global__ __launch_bounds__(512, 2)
void score_attn8(const unsigned short* __restrict__ pbuf,
                 const unsigned short* __restrict__ xb,
                 const unsigned short* __restrict__ gb,
                 const float* __restrict__ u, const float* __restrict__ v,
                 float* __restrict__ lpart, float* __restrict__ Apart) {
    extern __shared__ __align__(16) unsigned short lds_pg[];

    const int bid = blockIdx.x;
    const int logical = (bid & 7) * 32 + (bid >> 3);
    const int b  = logical >> 4;          // 0..15
    const int it = (logical >> 2) & 3;    // i-tile (256 rows)
    const int jt = logical & 3;           // j-tile (256 cols)

    const int tid = threadIdx.x, lane = tid & 63, w = tid >> 6;
    const int fr = lane & 15, ls = lane >> 4, f7 = fr & 7;

    const int ssl   = ((tid & 7) ^ ((tid >> 3) & 7)) * 8;      // elements
    const int soff0 = (tid >> 3) * 1024 + ssl;
    const int soff1 = soff0 + 64 * 1024;
    const int dstw  = w * 512;                                 // u16

    const unsigned short* pA0 = pbuf + (size_t)(b * 1024 + it * 256) * 1024;
    const unsigned short* pA1 = pA0  + (size_t)128 * 1024;
    const unsigned short* pB0 = xb   + (size_t)(b * 1024 + jt * 256) * 1024;
    const unsigned short* pB1 = pB0  + (size_t)128 * 1024;

    const int aregw = (w >> 2) * 8192;
    const int bregw = 16384 + ((w & 3) >> 1) * 8192;
    const int bro   = (w & 1) * 64;
    const int sl0   = (ls ^ f7) << 3;
    const int sl1   = ((4 + ls) ^ f7) << 3;

    f32x4 acc[8][4];
    frag8 af[4][2], bf[4][2];

    MAIN_LOOP_8PHASE(pA0, pA1, pB0, pB1)

    // epilogue: p = exp((S + u[i] + v[j])*scale); reduce p and p*G over cols
    const float scale = 0.03125f;   // 1/sqrt(1024)
    const int wm = (w >> 2) * 128, wn = (w & 3) * 64;
    const float* ub = u + (size_t)b * T_ + it * 256 + wm;
    const float* vb = v + (size_t)b * T_ + jt * 256 + wn;

    float vval[4];
#pragma unroll
    for (int j = 0; j < 4; ++j) vval[j] = vb[j * 16 + fr];

    const unsigned short* Gt =
        gb + ((size_t)((b * 4 + it) * 4 + jt) << 16) + tid * 8;

    const int i0b = it * 2 + (w >> 2);
    const int tch = jt * 4 + (w & 3);
    const size_t base = ((size_t)(b * 8 + i0b) * 16 + tch) * 128;
    float* lrow = lpart + base;
    float* Arow = Apart + base;

#pragma unroll
    for (int i = 0; i < 8; ++i) {
        float uval[4];
#pragma unroll
        for (int r = 0; r < 4; ++r) uval[r] = ub[i * 16 + ls * 4 + r];
        float lp[4] = {0.f, 0.f, 0.f, 0.f}, Ap[4] = {0.f, 0.f, 0.f, 0.f};
#pragma unroll
        for (int jp = 0; jp < 2; ++jp) {
            u16x8 gv = *(const u16x8*)(Gt + (size_t)(i * 2 + jp) * 4096);
#pragma unroll
            for (int e = 0; e < 8; ++e) {
                const int j = jp * 2 + (e >> 2), r = e & 3;
                float p = __expf((acc[i][j][r] + uval[r] + vval[j]) * scale);
                lp[r] += p;
                Ap[r] += p * bf2f(gv[e]);
            }
        }
#pragma unroll
        for (int m = 1; m < 16; m <<= 1) {
#pragma unroll
            for (int r = 0; r < 4; ++r) {
                lp[r] += __shfl_xor(lp[r], m);
                Ap[r] += __shfl_xor(Ap[r], m);
            }
        }
        if (fr == 0) {
#pragma unroll
            for (int r = 0; r < 4; ++r) {
                const int row = i * 16 + ls * 4 + r;
                lrow[row] = lp[r];
                Arow[row] = Ap[r];
            }
        }
    }
}

// ---------------------------------------------------------------------------
// K4: finalize — out[b] = bfc + sum_i (sum_t Apart)/(sum_t lpart).
// Fixed summation order -> bit-deterministic.  grid (16) block 256.
// ---------------------------------------------------------------------------
__global__ __launch_bounds__(256)
void finalize(const float* __restrict__ lpart, const float* __restrict__ Apart,
              const float* __restrict__ bfc, float* __restrict__ out) {
    const int b = blockIdx.x;
    const int tid = threadIdx.x, lane = tid & 63, wave = tid >> 6;
    float s = 0.f;
#pragma unroll
    for (int p = 0; p < 4; ++p) {
        const int rg = tid + p * 256;          // 0..1023 (row index within b)
        const int i0b = rg >> 7, row = rg & 127;
        const size_t base = ((size_t)b * 8 + i0b) * 2048 + row;
        float lsum = 0.f, Asum = 0.f;
#pragma unroll
        for (int t = 0; t < 16; ++t) {         // 64-col chunks, fixed order
            lsum += lpart[base + (size_t)t * 128];
            Asum += Apart[base + (size_t)t * 128];
        }
        s += Asum / lsum;
    }
#pragma unroll
    for (int off = 32; off; off >>= 1) s += __shfl_down(s, off);
    __shared__ float ws_[4];
    if (lane == 0) ws_[wave] = s;
    __syncthreads();
    if (tid == 0) out[b] = ws_[0] + ws_[1] + ws_[2] + ws_[3] + bfc[0];
}

extern "C" void kernel_launch(void* const* d_in, const int* in_sizes, int n_in,
                              void* d_out, int out_size, void* d_ws, size_t ws_size,
                              hipStream_t stream) {
    const float* x   = (const float*)d_in[0];
    const float* Wq  = (const float*)d_in[1];
    const float* bq  = (const float*)d_in[2];
    const float* Wk  = (const float*)d_in[3];
    const float* bk  = (const float*)d_in[4];
    const float* Wv  = (const float*)d_in[5];
    const float* bv  = (const float*)d_in[6];
    const float* Wfc = (const float*)d_in[7];
    const float* bfc = (const float*)d_in[8];
    float* out = (float*)d_out;

    // one-time: allow 128 KiB dynamic LDS (host-side, capture-safe)
    static bool attr_set = false;
    if (!attr_set) {
        hipFuncSetAttribute((const void*)pg_gemm8,
                            hipFuncAttributeMaxDynamicSharedMemorySize, 131072);
        hipFuncSetAttribute((const void*)score_attn8,
                            hipFuncAttributeMaxDynamicSharedMemorySize, 131072);
        attr_set = true;
    }

    // workspace layout (~110.4 MB), every byte written before read each call:
    char* ws = (char*)d_ws;
    unsigned short* xb    = (unsigned short*)ws;                   // 32 MB
    unsigned short* wqb   = xb   + (size_t)B_ * T_ * D_;           // 2 MB
    unsigned short* wkb   = wqb  + (size_t)D_ * D_;                // 2 MB
    unsigned short* wvb   = wkb  + (size_t)D_ * D_;                // 2 MB
    unsigned short* wfcb  = wvb  + (size_t)D_ * D_;                // 2 MB
    unsigned short* ntb   = wfcb + (size_t)D_ * D_;                // 2 MB
    unsigned short* mb    = ntb  + (size_t)D_ * D_;                // 2 MB
    unsigned short* pb    = mb   + (size_t)D_ * D_;                // 32 MB
    unsigned short* gbuf  = pb   + (size_t)B_ * T_ * D_;           // 32 MB
    float*          w1    = (float*)(gbuf + (size_t)B_ * T_ * T_); // 4 KB
    float*          w2    = w1 + D_;                               // 4 KB
    float*          cvec  = w2 + D_;                               // 4 KB
    float*          bkbq  = cvec + D_;                             // 16 B
    float*          u     = bkbq + 4;                              // 64 KB
    float*          v     = u + (size_t)B_ * T_;                   // 64 KB
    float*          lpart = v + (size_t)B_ * T_;                   // 1 MB
    float*          Apart = lpart + (size_t)B_ * 8 * 8 * 2 * 128;  // 1 MB

    cvt_w4     <<<dim3(4096),      256, 0,      stream>>>(Wq, Wk, Wv, Wfc, wqb, wkb, wvb, wfcb);
    wvec       <<<dim3(256, 4),    256, 0,      stream>>>(Wq, Wk, Wfc, bq, bk, bv, w1, w2, cvec, bkbq);
    cvt_x_uv   <<<dim3(4096),      256, 0,      stream>>>(x, xb, w1, w2, bkbq, u, v);
    small_gemm <<<dim3(8, 8, 2),   256, 0,      stream>>>(wqb, wkb, wfcb, wvb, ntb, mb);
    pg_gemm8   <<<dim3(512),       512, 131072, stream>>>(xb, ntb, mb, cvec, pb, gbuf);
    score_attn8<<<dim3(256),       512, 131072, stream>>>(pb, xb, gbuf, u, v, lpart, Apart);
    finalize   <<<dim3(B_),        256, 0,      stream>>>(lpart, Apart, bfc, out);
}